// Round 3
// baseline (1316.269 us; speedup 1.0000x reference)
//
#include <hip/hip_runtime.h>

#define MDIM 128
#define NCOL 20000
#define NEDGE 320000
#define NITER 30
#define FKAPPA 0.99f

typedef unsigned int uint;
typedef unsigned short ushort;
typedef __attribute__((ext_vector_type(8))) short short8;
typedef __attribute__((ext_vector_type(4))) float f32x4;

__device__ __forceinline__ float bf2f(ushort b){
    uint u = ((uint)b) << 16;
    return __builtin_bit_cast(float, u);
}
__device__ __forceinline__ ushort f2bf(float f){
    uint u = __builtin_bit_cast(uint, f);
    uint r = (u + 0x7fffu + ((u >> 16) & 1u)) >> 16;
    return (ushort)r;
}

// ---------------- CSC build ----------------
__global__ void k_zero(int* __restrict__ p){
    int i = blockIdx.x * 256 + threadIdx.x;
    if (i < 2 * NCOL) p[i] = 0;
}

__global__ void k_hist(const int* __restrict__ cols, int* __restrict__ cnt){
    int e = blockIdx.x * 256 + threadIdx.x;
    if (e < NEDGE) atomicAdd(&cnt[cols[e]], 1);
}

__global__ void k_scan(const int* __restrict__ cnt, int* __restrict__ start){
    __shared__ int lds[256];
    const int SEG = (NCOL + 255) / 256; // 79
    int t = threadIdx.x;
    int lo = t * SEG;
    int hi = min(lo + SEG, NCOL);
    int s = 0;
    for (int i = lo; i < hi; ++i) s += cnt[i];
    lds[t] = s;
    __syncthreads();
    for (int off = 1; off < 256; off <<= 1){
        int v = (t >= off) ? lds[t - off] : 0;
        __syncthreads();
        lds[t] += v;
        __syncthreads();
    }
    int run = (t > 0) ? lds[t - 1] : 0;
    for (int i = lo; i < hi; ++i){ start[i] = run; run += cnt[i]; }
    if (hi == NCOL && lo < NCOL) start[NCOL] = run;
}

// edges[p] = { row, f32_bits(val) }
__global__ void k_scatter(const int* __restrict__ rows, const int* __restrict__ cols,
                          const float* __restrict__ vals, const int* __restrict__ start,
                          int* __restrict__ cursor, uint2* __restrict__ edges){
    int e = blockIdx.x * 256 + threadIdx.x;
    if (e < NEDGE){
        int c = cols[e];
        int p = start[c] + atomicAdd(&cursor[c], 1);
        edges[p] = make_uint2((uint)rows[e], __builtin_bit_cast(uint, vals[e]));
    }
}

// ---------------- L-inf projection of W (row-wise simplex proj on |W|) ---------
__global__ void k_project(const float* __restrict__ W, ushort* __restrict__ Wp){
    int row = blockIdx.x * 4 + (threadIdx.x >> 6);
    int l = threadIdx.x & 63;
    const float* wr = W + row * MDIM;
    float w0 = wr[l], w1 = wr[l + 64];
    float a0 = fabsf(w0), a1 = fabsf(w1);
    float s = a0 + a1, mx = fmaxf(a0, a1);
    for (int off = 32; off; off >>= 1){
        s += __shfl_xor(s, off);
        mx = fmaxf(mx, __shfl_xor(mx, off));
    }
    if (s > FKAPPA){
        float tlo = 0.f, thi = mx;
        for (int it = 0; it < 48; ++it){
            float th = 0.5f * (tlo + thi);
            float f = fmaxf(a0 - th, 0.f) + fmaxf(a1 - th, 0.f);
            for (int off = 32; off; off >>= 1) f += __shfl_xor(f, off);
            if (f > FKAPPA) tlo = th; else thi = th;
        }
        float th = 0.5f * (tlo + thi);
        w0 = copysignf(fmaxf(a0 - th, 0.f), w0);
        w1 = copysignf(fmaxf(a1 - th, 0.f), w1);
    }
    Wp[row * MDIM + l] = f2bf(w0);
    Wp[row * MDIM + l + 64] = f2bf(w1);
}

__global__ void k_cvt(const float* __restrict__ src, ushort* __restrict__ dst){
    int i = blockIdx.x * 256 + threadIdx.x;
    if (i < MDIM * MDIM) dst[i] = f2bf(src[i]);
}

// ---------------- transposes f32 [128][N] <-> bf16 [N][128] ----------------
__global__ void k_tin(const float* __restrict__ X0, const float* __restrict__ U,
                      ushort* __restrict__ Xt, ushort* __restrict__ Ut){
    __shared__ ushort tile[128 * 66];
    const float* src = blockIdx.y ? U : X0;
    ushort* dst = blockIdx.y ? Ut : Xt;
    int c0 = blockIdx.x * 64;
    int t = threadIdx.x;
    for (int it = 0; it < 32; ++it){
        int le = it * 256 + t;
        int j = le & 63, m = le >> 6;
        int c = c0 + j;
        tile[m * 66 + j] = (c < NCOL) ? f2bf(src[m * NCOL + c]) : (ushort)0;
    }
    __syncthreads();
    for (int it = 0; it < 32; ++it){
        int le = it * 256 + t;
        int m = le & 127, jc = le >> 7;
        int c = c0 + jc;
        if (c < NCOL) dst[c * MDIM + m] = tile[m * 66 + jc];
    }
}

__global__ void k_tout(const ushort* __restrict__ Xt, float* __restrict__ out){
    __shared__ ushort tile[128 * 66];
    int c0 = blockIdx.x * 64;
    int t = threadIdx.x;
    for (int it = 0; it < 32; ++it){
        int le = it * 256 + t;
        int m = le & 127, jc = le >> 7;
        int c = c0 + jc;
        tile[m * 66 + jc] = (c < NCOL) ? Xt[c * MDIM + m] : (ushort)0;
    }
    __syncthreads();
    for (int it = 0; it < 32; ++it){
        int le = it * 256 + t;
        int j = le & 63, m = le >> 6;
        int c = c0 + j;
        if (c < NCOL) out[m * NCOL + c] = bf2f(tile[m * 66 + j]);
    }
}

// ---------------- fused iteration:  out[c][m] = phi( sum_k (X@A)^T[c][k] * Mat[m][k] + Bt[c][m] )
// MODE 0: setup (out = Bt bf16, no bias, no relu).  MODE 1: iteration (bias+relu).
template<int MODE>
__global__ __launch_bounds__(512, 2) void k_fused(const ushort* __restrict__ Xt_in,
                        const ushort* __restrict__ Mat,
                        const ushort* __restrict__ Bt,
                        ushort* __restrict__ outp,
                        const int* __restrict__ start,
                        const uint2* __restrict__ edges){
    __shared__ alignas(16) char smem[48 * 1024];
    char* WL = smem;             // 32KB: Mat[128][128] bf16, XOR-swizzled rows
    char* GL = smem + 32 * 1024; // 16KB: G[64][128] bf16, XOR-swizzled rows
    int t = threadIdx.x;
    int w = t >> 6, l = t & 63;
    int c0 = blockIdx.x * 64;

    // stage Mat -> LDS (row-major [m][k], swizzle byte ^= (row&7)<<4)
    {
        const uint2* m8 = (const uint2*)Mat; // 4096 x 8B
        for (int it = 0; it < 8; ++it){
            int idx = it * 512 + t;
            int byteoff = idx * 8;
            int row = byteoff >> 8;
            *(uint2*)(WL + (byteoff ^ ((row & 7) << 4))) = m8[idx];
        }
    }

    // gather phase: G[j][:] = sum_e val_e * Xt[row_e][:]   (8 columns per wave)
    {
        const uint* xin = (const uint*)Xt_in; // 64 uints per 128-bf16 row
        for (int jj = 0; jj < 8; ++jj){
            int j = w * 8 + jj;
            int c = c0 + j;
            float a0 = 0.f, a1 = 0.f;
            if (c < NCOL){
                int s = start[c], e = start[c + 1];
                int k = s;
                for (; k + 4 <= e; k += 4){
                    uint2 p0 = edges[k], p1 = edges[k+1], p2 = edges[k+2], p3 = edges[k+3];
                    float v0 = __builtin_bit_cast(float, p0.y);
                    float v1 = __builtin_bit_cast(float, p1.y);
                    float v2 = __builtin_bit_cast(float, p2.y);
                    float v3 = __builtin_bit_cast(float, p3.y);
                    uint x0 = xin[p0.x * 64 + l];
                    uint x1 = xin[p1.x * 64 + l];
                    uint x2 = xin[p2.x * 64 + l];
                    uint x3 = xin[p3.x * 64 + l];
                    a0 += v0 * bf2f((ushort)(x0 & 0xffffu)); a1 += v0 * bf2f((ushort)(x0 >> 16));
                    a0 += v1 * bf2f((ushort)(x1 & 0xffffu)); a1 += v1 * bf2f((ushort)(x1 >> 16));
                    a0 += v2 * bf2f((ushort)(x2 & 0xffffu)); a1 += v2 * bf2f((ushort)(x2 >> 16));
                    a0 += v3 * bf2f((ushort)(x3 & 0xffffu)); a1 += v3 * bf2f((ushort)(x3 >> 16));
                }
                for (; k < e; ++k){
                    uint2 p = edges[k];
                    float v = __builtin_bit_cast(float, p.y);
                    uint x = xin[p.x * 64 + l];
                    a0 += v * bf2f((ushort)(x & 0xffffu)); a1 += v * bf2f((ushort)(x >> 16));
                }
            }
            uint packed = (uint)f2bf(a0) | ((uint)f2bf(a1) << 16);
            int byteoff = j * 256 + l * 4;
            *(uint*)(GL + (byteoff ^ ((j & 7) << 4))) = packed;
        }
    }
    __syncthreads();

    // GEMM phase: out[64 x 128] = G[64 x 128] * Mat^T ; wave w: c-tile (w&3), m-half (w>>2)
    {
        int cw = w & 3, mh = w >> 2;
        int arow = cw * 16 + (l & 15);
        int klane = (l >> 4) * 16;          // byte offset of this lane's k-chunk
        int asw = (arow & 7) << 4;
        short8 afr[4];
        for (int kc = 0; kc < 4; ++kc)
            afr[kc] = *(const short8*)(GL + ((arow * 256 + kc * 64 + klane) ^ asw));
        for (int mt = 0; mt < 4; ++mt){
            int m = mh * 64 + mt * 16 + (l & 15);
            int msw = (m & 7) << 4;
            f32x4 acc = {0.f, 0.f, 0.f, 0.f};
            for (int kc = 0; kc < 4; ++kc){
                short8 bfr = *(const short8*)(WL + ((m * 256 + kc * 64 + klane) ^ msw));
                acc = __builtin_amdgcn_mfma_f32_16x16x32_bf16(afr[kc], bfr, acc, 0, 0, 0);
            }
            int crow_base = c0 + cw * 16 + ((l >> 4) << 2);
            for (int q = 0; q < 4; ++q){
                int c = crow_base + q;
                if (c < NCOL){
                    float val = acc[q];
                    if (MODE == 1){
                        val += bf2f(Bt[c * MDIM + m]);
                        val = fmaxf(val, 0.f);
                    }
                    outp[c * MDIM + m] = f2bf(val);
                }
            }
        }
    }
}

extern "C" void kernel_launch(void* const* d_in, const int* in_sizes, int n_in,
                              void* d_out, int out_size, void* d_ws, size_t ws_size,
                              hipStream_t stream){
    const float* X0 = (const float*)d_in[0];
    const float* U  = (const float*)d_in[1];
    const float* W  = (const float*)d_in[2];
    const float* Om = (const float*)d_in[3];
    const float* Av = (const float*)d_in[4];
    const int*   Ar = (const int*)d_in[5];
    const int*   Ac = (const int*)d_in[6];
    (void)in_sizes; (void)n_in; (void)out_size; (void)ws_size;

    // ---- workspace layout (total ~7.9 MB) ----
    char* ws = (char*)d_ws;
    size_t off = 0;
    auto alloc = [&](size_t bytes) -> char* {
        char* p = ws + off;
        off += (bytes + 255) & ~(size_t)255;
        return p;
    };
    int*    start = (int*)alloc((NCOL + 1) * 4);        //  80 KB
    uint2*  edges = (uint2*)alloc(NEDGE * 8);           //  2.56 MB
    ushort* Wp    = (ushort*)alloc(MDIM * MDIM * 2);    //  32 KB
    ushort* Omb   = (ushort*)alloc(MDIM * MDIM * 2);    //  32 KB
    ushort* P0    = (ushort*)alloc(NCOL * MDIM * 2);    //  5.12 MB

    // cnt/cursor live in P0's space (dead before k_tin writes it)
    int* cnt    = (int*)P0;
    int* cursor = cnt + NCOL;

    // d_out (10.24 MB f32) hosts P1 + Bt until the final transpose
    ushort* P1   = (ushort*)d_out;
    ushort* BtBF = (ushort*)((char*)d_out + NCOL * MDIM * 2);

    k_zero<<<(2 * NCOL + 255) / 256, 256, 0, stream>>>(cnt);
    k_hist<<<(NEDGE + 255) / 256, 256, 0, stream>>>(Ac, cnt);
    k_scan<<<1, 256, 0, stream>>>(cnt, start);
    k_scatter<<<(NEDGE + 255) / 256, 256, 0, stream>>>(Ar, Ac, Av, start, cursor, edges);
    k_project<<<32, 256, 0, stream>>>(W, Wp);
    k_cvt<<<64, 256, 0, stream>>>(Om, Omb);
    // Xt -> P0 (overwrites cnt/cursor, dead after scatter), Ut -> P1
    k_tin<<<dim3(313, 2), 256, 0, stream>>>(X0, U, P0, P1);
    // Bt = ((Omega_1 @ U) @ A)^T, stored bf16
    k_fused<0><<<313, 512, 0, stream>>>(P1, Omb, nullptr, BtBF, start, edges);
    const ushort* cur = P0; ushort* nxt = P1;
    for (int i = 0; i < NITER; ++i){
        k_fused<1><<<313, 512, 0, stream>>>(cur, Wp, BtBF, nxt, start, edges);
        ushort* tmp = (ushort*)cur; cur = nxt; nxt = tmp;
    }
    // NITER even -> cur == P0 (ws); k_tout overwrites all of d_out (P1/Bt dead)
    k_tout<<<313, 256, 0, stream>>>(cur, (float*)d_out);
}

// Round 4
// 907.323 us; speedup vs baseline: 1.4507x; 1.4507x over previous
//
#include <hip/hip_runtime.h>

#define MDIM 128
#define NCOL 20000
#define NEDGE 320000
#define NITER 30
#define FKAPPA 0.99f

typedef unsigned int uint;
typedef unsigned short ushort;
typedef __attribute__((ext_vector_type(8))) short short8;
typedef __attribute__((ext_vector_type(4))) float f32x4;

__device__ __forceinline__ float bf2f(ushort b){
    uint u = ((uint)b) << 16;
    return __builtin_bit_cast(float, u);
}
__device__ __forceinline__ ushort f2bf(float f){
    uint u = __builtin_bit_cast(uint, f);
    uint r = (u + 0x7fffu + ((u >> 16) & 1u)) >> 16;
    return (ushort)r;
}

// ---------------- CSC build ----------------
__global__ void k_zero(int* __restrict__ p){
    int i = blockIdx.x * 256 + threadIdx.x;
    if (i < 2 * NCOL) p[i] = 0;
}

__global__ void k_hist(const int* __restrict__ cols, int* __restrict__ cnt){
    int e = blockIdx.x * 256 + threadIdx.x;
    if (e < NEDGE) atomicAdd(&cnt[cols[e]], 1);
}

__global__ void k_scan(const int* __restrict__ cnt, int* __restrict__ start){
    __shared__ int lds[256];
    const int SEG = (NCOL + 255) / 256; // 79
    int t = threadIdx.x;
    int lo = t * SEG;
    int hi = min(lo + SEG, NCOL);
    int s = 0;
    for (int i = lo; i < hi; ++i) s += cnt[i];
    lds[t] = s;
    __syncthreads();
    for (int off = 1; off < 256; off <<= 1){
        int v = (t >= off) ? lds[t - off] : 0;
        __syncthreads();
        lds[t] += v;
        __syncthreads();
    }
    int run = (t > 0) ? lds[t - 1] : 0;
    for (int i = lo; i < hi; ++i){ start[i] = run; run += cnt[i]; }
    if (hi == NCOL && lo < NCOL) start[NCOL] = run;
}

// edges[p] = { row, f32_bits(val) }
__global__ void k_scatter(const int* __restrict__ rows, const int* __restrict__ cols,
                          const float* __restrict__ vals, const int* __restrict__ start,
                          int* __restrict__ cursor, uint2* __restrict__ edges){
    int e = blockIdx.x * 256 + threadIdx.x;
    if (e < NEDGE){
        int c = cols[e];
        int p = start[c] + atomicAdd(&cursor[c], 1);
        edges[p] = make_uint2((uint)rows[e], __builtin_bit_cast(uint, vals[e]));
    }
}

// ---------------- L-inf projection of W ----------------
__global__ void k_project(const float* __restrict__ W, ushort* __restrict__ Wp){
    int row = blockIdx.x * 4 + (threadIdx.x >> 6);
    int l = threadIdx.x & 63;
    const float* wr = W + row * MDIM;
    float w0 = wr[l], w1 = wr[l + 64];
    float a0 = fabsf(w0), a1 = fabsf(w1);
    float s = a0 + a1, mx = fmaxf(a0, a1);
    for (int off = 32; off; off >>= 1){
        s += __shfl_xor(s, off);
        mx = fmaxf(mx, __shfl_xor(mx, off));
    }
    if (s > FKAPPA){
        float tlo = 0.f, thi = mx;
        for (int it = 0; it < 48; ++it){
            float th = 0.5f * (tlo + thi);
            float f = fmaxf(a0 - th, 0.f) + fmaxf(a1 - th, 0.f);
            for (int off = 32; off; off >>= 1) f += __shfl_xor(f, off);
            if (f > FKAPPA) tlo = th; else thi = th;
        }
        float th = 0.5f * (tlo + thi);
        w0 = copysignf(fmaxf(a0 - th, 0.f), w0);
        w1 = copysignf(fmaxf(a1 - th, 0.f), w1);
    }
    Wp[row * MDIM + l] = f2bf(w0);
    Wp[row * MDIM + l + 64] = f2bf(w1);
}

__global__ void k_cvt(const float* __restrict__ src, ushort* __restrict__ dst){
    int i = blockIdx.x * 256 + threadIdx.x;
    if (i < MDIM * MDIM) dst[i] = f2bf(src[i]);
}

// ---------------- transposes f32 [128][N] <-> bf16 [N][128] ----------------
__global__ void k_tin(const float* __restrict__ X0, const float* __restrict__ U,
                      ushort* __restrict__ Xt, ushort* __restrict__ Ut){
    __shared__ ushort tile[128 * 66];
    const float* src = blockIdx.y ? U : X0;
    ushort* dst = blockIdx.y ? Ut : Xt;
    int c0 = blockIdx.x * 64;
    int t = threadIdx.x;
    for (int it = 0; it < 32; ++it){
        int le = it * 256 + t;
        int j = le & 63, m = le >> 6;
        int c = c0 + j;
        tile[m * 66 + j] = (c < NCOL) ? f2bf(src[m * NCOL + c]) : (ushort)0;
    }
    __syncthreads();
    for (int it = 0; it < 32; ++it){
        int le = it * 256 + t;
        int m = le & 127, jc = le >> 7;
        int c = c0 + jc;
        if (c < NCOL) dst[c * MDIM + m] = tile[m * 66 + jc];
    }
}

__global__ void k_tout(const ushort* __restrict__ Xt, float* __restrict__ out){
    __shared__ ushort tile[128 * 66];
    int c0 = blockIdx.x * 64;
    int t = threadIdx.x;
    for (int it = 0; it < 32; ++it){
        int le = it * 256 + t;
        int m = le & 127, jc = le >> 7;
        int c = c0 + jc;
        tile[m * 66 + jc] = (c < NCOL) ? Xt[c * MDIM + m] : (ushort)0;
    }
    __syncthreads();
    for (int it = 0; it < 32; ++it){
        int le = it * 256 + t;
        int j = le & 63, m = le >> 6;
        int c = c0 + j;
        if (c < NCOL) out[m * NCOL + c] = bf2f(tile[m * 66 + j]);
    }
}

// ---------------- fused iteration ----------------
// out[c][m] = phi( sum_k (X@A)^T[c][k] * Mat[m][k] + Bt[c][m] )
// 32 columns per block, 4 waves. Gather: 16 lanes per edge (dwordx4), 4 edges/iter.
template<int MODE>
__global__ __launch_bounds__(256, 4) void k_fused(const ushort* __restrict__ Xt_in,
                        const ushort* __restrict__ Mat,
                        const ushort* __restrict__ Bt,
                        ushort* __restrict__ outp,
                        const int* __restrict__ start,
                        const uint2* __restrict__ edges){
    __shared__ alignas(16) char WL[32 * 1024]; // Mat[128][128] bf16, XOR-swizzled rows
    __shared__ alignas(16) char GL[8 * 1024];  // G[32][128] bf16, XOR-swizzled rows
    int t = threadIdx.x;
    int w = t >> 6, l = t & 63;
    int c0 = blockIdx.x * 32;

    // stage Mat -> LDS (row-major [m][k], swizzle byte ^= (row&7)<<4)
    {
        const uint4* m16 = (const uint4*)Mat; // 2048 x 16B
        for (int it = 0; it < 8; ++it){
            int idx = it * 256 + t;
            int byteoff = idx * 16;
            int row = byteoff >> 8;
            *(uint4*)(WL + (byteoff ^ ((row & 7) << 4))) = m16[idx];
        }
    }

    // gather phase: 8 columns per wave; per iter 4 edges x (16 lanes x 16B)
    {
        int g = l >> 4;     // edge slot within iter
        int sub = l & 15;   // 16B chunk within row
        for (int jj = 0; jj < 8; ++jj){
            int j = w * 8 + jj;
            int c = c0 + j;
            int s = start[c], e = start[c + 1];
            float acc[8] = {0.f,0.f,0.f,0.f,0.f,0.f,0.f,0.f};
            int k = s;
            // main: 8 edges per iter, both gathers issued before FMAs
            for (; k + 8 <= e; k += 8){
                uint2 pA = edges[k + g];
                uint2 pB = edges[k + 4 + g];
                uint4 xA = *(const uint4*)(Xt_in + (size_t)pA.x * 128 + sub * 8);
                uint4 xB = *(const uint4*)(Xt_in + (size_t)pB.x * 128 + sub * 8);
                float vA = __builtin_bit_cast(float, pA.y);
                float vB = __builtin_bit_cast(float, pB.y);
                acc[0] += vA * bf2f((ushort)(xA.x & 0xffffu)); acc[1] += vA * bf2f((ushort)(xA.x >> 16));
                acc[2] += vA * bf2f((ushort)(xA.y & 0xffffu)); acc[3] += vA * bf2f((ushort)(xA.y >> 16));
                acc[4] += vA * bf2f((ushort)(xA.z & 0xffffu)); acc[5] += vA * bf2f((ushort)(xA.z >> 16));
                acc[6] += vA * bf2f((ushort)(xA.w & 0xffffu)); acc[7] += vA * bf2f((ushort)(xA.w >> 16));
                acc[0] += vB * bf2f((ushort)(xB.x & 0xffffu)); acc[1] += vB * bf2f((ushort)(xB.x >> 16));
                acc[2] += vB * bf2f((ushort)(xB.y & 0xffffu)); acc[3] += vB * bf2f((ushort)(xB.y >> 16));
                acc[4] += vB * bf2f((ushort)(xB.z & 0xffffu)); acc[5] += vB * bf2f((ushort)(xB.z >> 16));
                acc[6] += vB * bf2f((ushort)(xB.w & 0xffffu)); acc[7] += vB * bf2f((ushort)(xB.w >> 16));
            }
            // tail: guarded 4-edge iters
            for (; k < e; k += 4){
                int ke = k + g;
                uint2 p = edges[min(ke, e - 1)];
                float v = (ke < e) ? __builtin_bit_cast(float, p.y) : 0.f;
                uint4 x = *(const uint4*)(Xt_in + (size_t)p.x * 128 + sub * 8);
                acc[0] += v * bf2f((ushort)(x.x & 0xffffu)); acc[1] += v * bf2f((ushort)(x.x >> 16));
                acc[2] += v * bf2f((ushort)(x.y & 0xffffu)); acc[3] += v * bf2f((ushort)(x.y >> 16));
                acc[4] += v * bf2f((ushort)(x.z & 0xffffu)); acc[5] += v * bf2f((ushort)(x.z >> 16));
                acc[6] += v * bf2f((ushort)(x.w & 0xffffu)); acc[7] += v * bf2f((ushort)(x.w >> 16));
            }
            // reduce 4 groups -> all lanes hold final
            #pragma unroll
            for (int i = 0; i < 8; ++i){
                acc[i] += __shfl_xor(acc[i], 16);
                acc[i] += __shfl_xor(acc[i], 32);
            }
            if (l < 16){
                uint4 pk;
                pk.x = (uint)f2bf(acc[0]) | ((uint)f2bf(acc[1]) << 16);
                pk.y = (uint)f2bf(acc[2]) | ((uint)f2bf(acc[3]) << 16);
                pk.z = (uint)f2bf(acc[4]) | ((uint)f2bf(acc[5]) << 16);
                pk.w = (uint)f2bf(acc[6]) | ((uint)f2bf(acc[7]) << 16);
                *(uint4*)(GL + ((j * 256 + sub * 16) ^ ((j & 7) << 4))) = pk;
            }
        }
    }
    __syncthreads();

    // GEMM phase: out[32 x 128] = G * Mat^T ; wave w: c-tile (w&1), m-half (w>>1)
    {
        int cw = w & 1, mh = w >> 1;
        int arow = cw * 16 + (l & 15);
        int klane = (l >> 4) * 16;
        int asw = (arow & 7) << 4;
        short8 afr[4];
        for (int kc = 0; kc < 4; ++kc)
            afr[kc] = *(const short8*)(GL + ((arow * 256 + kc * 64 + klane) ^ asw));
        for (int mt = 0; mt < 4; ++mt){
            int m = mh * 64 + mt * 16 + (l & 15);
            int msw = (m & 7) << 4;
            f32x4 acc4 = {0.f, 0.f, 0.f, 0.f};
            for (int kc = 0; kc < 4; ++kc){
                short8 bfr = *(const short8*)(WL + ((m * 256 + kc * 64 + klane) ^ msw));
                acc4 = __builtin_amdgcn_mfma_f32_16x16x32_bf16(afr[kc], bfr, acc4, 0, 0, 0);
            }
            int crow_base = c0 + cw * 16 + ((l >> 4) << 2);
            #pragma unroll
            for (int q = 0; q < 4; ++q){
                int c = crow_base + q;
                float val = acc4[q];
                if (MODE == 1){
                    val += bf2f(Bt[c * MDIM + m]);
                    val = fmaxf(val, 0.f);
                }
                outp[c * MDIM + m] = f2bf(val);
            }
        }
    }
}

extern "C" void kernel_launch(void* const* d_in, const int* in_sizes, int n_in,
                              void* d_out, int out_size, void* d_ws, size_t ws_size,
                              hipStream_t stream){
    const float* X0 = (const float*)d_in[0];
    const float* U  = (const float*)d_in[1];
    const float* W  = (const float*)d_in[2];
    const float* Om = (const float*)d_in[3];
    const float* Av = (const float*)d_in[4];
    const int*   Ar = (const int*)d_in[5];
    const int*   Ac = (const int*)d_in[6];
    (void)in_sizes; (void)n_in; (void)out_size; (void)ws_size;

    char* ws = (char*)d_ws;
    size_t off = 0;
    auto alloc = [&](size_t bytes) -> char* {
        char* p = ws + off;
        off += (bytes + 255) & ~(size_t)255;
        return p;
    };
    int*    start = (int*)alloc((NCOL + 1) * 4);        //  80 KB
    uint2*  edges = (uint2*)alloc(NEDGE * 8);           //  2.56 MB
    ushort* Wp    = (ushort*)alloc(MDIM * MDIM * 2);    //  32 KB
    ushort* Omb   = (ushort*)alloc(MDIM * MDIM * 2);    //  32 KB
    ushort* P0    = (ushort*)alloc(NCOL * MDIM * 2);    //  5.12 MB

    // cnt/cursor live in P0's space (dead before k_tin writes it)
    int* cnt    = (int*)P0;
    int* cursor = cnt + NCOL;

    // d_out (10.24 MB f32) hosts P1 + Bt until the final transpose
    ushort* P1   = (ushort*)d_out;
    ushort* BtBF = (ushort*)((char*)d_out + NCOL * MDIM * 2);

    k_zero<<<(2 * NCOL + 255) / 256, 256, 0, stream>>>(cnt);
    k_hist<<<(NEDGE + 255) / 256, 256, 0, stream>>>(Ac, cnt);
    k_scan<<<1, 256, 0, stream>>>(cnt, start);
    k_scatter<<<(NEDGE + 255) / 256, 256, 0, stream>>>(Ar, Ac, Av, start, cursor, edges);
    k_project<<<32, 256, 0, stream>>>(W, Wp);
    k_cvt<<<64, 256, 0, stream>>>(Om, Omb);
    k_tin<<<dim3(313, 2), 256, 0, stream>>>(X0, U, P0, P1);
    // Bt = ((Omega_1 @ U) @ A)^T, stored bf16
    k_fused<0><<<625, 256, 0, stream>>>(P1, Omb, nullptr, BtBF, start, edges);
    const ushort* cur = P0; ushort* nxt = P1;
    for (int i = 0; i < NITER; ++i){
        k_fused<1><<<625, 256, 0, stream>>>(cur, Wp, BtBF, nxt, start, edges);
        ushort* tmp = (ushort*)cur; cur = nxt; nxt = tmp;
    }
    // NITER even -> cur == P0 (ws); k_tout overwrites all of d_out (P1/Bt dead)
    k_tout<<<313, 256, 0, stream>>>(cur, (float*)d_out);
}

// Round 5
// 833.616 us; speedup vs baseline: 1.5790x; 1.0884x over previous
//
#include <hip/hip_runtime.h>

#define MDIM 128
#define NCOL 20000
#define NEDGE 320000
#define NITER 30
#define FKAPPA 0.99f

typedef unsigned int uint;
typedef unsigned short ushort;
typedef __attribute__((ext_vector_type(8))) short short8;
typedef __attribute__((ext_vector_type(4))) float f32x4;

__device__ __forceinline__ float bf2f(ushort b){
    uint u = ((uint)b) << 16;
    return __builtin_bit_cast(float, u);
}
__device__ __forceinline__ ushort f2bf(float f){
    uint u = __builtin_bit_cast(uint, f);
    uint r = (u + 0x7fffu + ((u >> 16) & 1u)) >> 16;
    return (ushort)r;
}

// ---------------- CSC build ----------------
__global__ void k_zero(int* __restrict__ p){
    int i = blockIdx.x * 256 + threadIdx.x;
    if (i < 2 * NCOL) p[i] = 0;
}

__global__ void k_hist(const int* __restrict__ cols, int* __restrict__ cnt){
    int e = blockIdx.x * 256 + threadIdx.x;
    if (e < NEDGE) atomicAdd(&cnt[cols[e]], 1);
}

__global__ void k_scan(const int* __restrict__ cnt, int* __restrict__ start){
    __shared__ int lds[256];
    const int SEG = (NCOL + 255) / 256; // 79
    int t = threadIdx.x;
    int lo = t * SEG;
    int hi = min(lo + SEG, NCOL);
    int s = 0;
    for (int i = lo; i < hi; ++i) s += cnt[i];
    lds[t] = s;
    __syncthreads();
    for (int off = 1; off < 256; off <<= 1){
        int v = (t >= off) ? lds[t - off] : 0;
        __syncthreads();
        lds[t] += v;
        __syncthreads();
    }
    int run = (t > 0) ? lds[t - 1] : 0;
    for (int i = lo; i < hi; ++i){ start[i] = run; run += cnt[i]; }
    if (hi == NCOL && lo < NCOL) start[NCOL] = run;
}

// edges[p] = { row, f32_bits(val) }
__global__ void k_scatter(const int* __restrict__ rows, const int* __restrict__ cols,
                          const float* __restrict__ vals, const int* __restrict__ start,
                          int* __restrict__ cursor, uint2* __restrict__ edges){
    int e = blockIdx.x * 256 + threadIdx.x;
    if (e < NEDGE){
        int c = cols[e];
        int p = start[c] + atomicAdd(&cursor[c], 1);
        edges[p] = make_uint2((uint)rows[e], __builtin_bit_cast(uint, vals[e]));
    }
}

// ---------------- L-inf projection of W ----------------
__global__ void k_project(const float* __restrict__ W, ushort* __restrict__ Wp){
    int row = blockIdx.x * 4 + (threadIdx.x >> 6);
    int l = threadIdx.x & 63;
    const float* wr = W + row * MDIM;
    float w0 = wr[l], w1 = wr[l + 64];
    float a0 = fabsf(w0), a1 = fabsf(w1);
    float s = a0 + a1, mx = fmaxf(a0, a1);
    for (int off = 32; off; off >>= 1){
        s += __shfl_xor(s, off);
        mx = fmaxf(mx, __shfl_xor(mx, off));
    }
    if (s > FKAPPA){
        float tlo = 0.f, thi = mx;
        for (int it = 0; it < 48; ++it){
            float th = 0.5f * (tlo + thi);
            float f = fmaxf(a0 - th, 0.f) + fmaxf(a1 - th, 0.f);
            for (int off = 32; off; off >>= 1) f += __shfl_xor(f, off);
            if (f > FKAPPA) tlo = th; else thi = th;
        }
        float th = 0.5f * (tlo + thi);
        w0 = copysignf(fmaxf(a0 - th, 0.f), w0);
        w1 = copysignf(fmaxf(a1 - th, 0.f), w1);
    }
    Wp[row * MDIM + l] = f2bf(w0);
    Wp[row * MDIM + l + 64] = f2bf(w1);
}

__global__ void k_cvt(const float* __restrict__ src, ushort* __restrict__ dst){
    int i = blockIdx.x * 256 + threadIdx.x;
    if (i < MDIM * MDIM) dst[i] = f2bf(src[i]);
}

// ---------------- transposes f32 [128][N] <-> bf16 [N][128] ----------------
__global__ void k_tin(const float* __restrict__ X0, const float* __restrict__ U,
                      ushort* __restrict__ Xt, ushort* __restrict__ Ut){
    __shared__ ushort tile[128 * 66];
    const float* src = blockIdx.y ? U : X0;
    ushort* dst = blockIdx.y ? Ut : Xt;
    int c0 = blockIdx.x * 64;
    int t = threadIdx.x;
    for (int it = 0; it < 32; ++it){
        int le = it * 256 + t;
        int j = le & 63, m = le >> 6;
        int c = c0 + j;
        tile[m * 66 + j] = (c < NCOL) ? f2bf(src[m * NCOL + c]) : (ushort)0;
    }
    __syncthreads();
    for (int it = 0; it < 32; ++it){
        int le = it * 256 + t;
        int m = le & 127, jc = le >> 7;
        int c = c0 + jc;
        if (c < NCOL) dst[c * MDIM + m] = tile[m * 66 + jc];
    }
}

__global__ void k_tout(const ushort* __restrict__ Xt, float* __restrict__ out){
    __shared__ ushort tile[128 * 66];
    int c0 = blockIdx.x * 64;
    int t = threadIdx.x;
    for (int it = 0; it < 32; ++it){
        int le = it * 256 + t;
        int m = le & 127, jc = le >> 7;
        int c = c0 + jc;
        tile[m * 66 + jc] = (c < NCOL) ? Xt[c * MDIM + m] : (ushort)0;
    }
    __syncthreads();
    for (int it = 0; it < 32; ++it){
        int le = it * 256 + t;
        int j = le & 63, m = le >> 6;
        int c = c0 + j;
        if (c < NCOL) out[m * NCOL + c] = bf2f(tile[m * 66 + j]);
    }
}

// ---------------- fused iteration ----------------
// out[c][m] = phi( sum_k (X@A)^T[c][k] * Mat[m][k] + Bt[c][m] )
// 16 columns per block (1250 blocks), 4 waves. Gather: 16 lanes/edge (dwordx4),
// main step = 16 edges (4 x-loads in flight), then 8, then guarded 4.
template<int MODE>
__global__ __launch_bounds__(256, 4) void k_fused(const ushort* __restrict__ Xt_in,
                        const ushort* __restrict__ Mat,
                        const ushort* __restrict__ Bt,
                        ushort* __restrict__ outp,
                        const int* __restrict__ start,
                        const uint2* __restrict__ edges){
    __shared__ alignas(16) char WL[32 * 1024]; // Mat[128][128] bf16, XOR-swizzled rows
    __shared__ alignas(16) char GL[4 * 1024];  // G[16][128] bf16, XOR-swizzled rows
    int t = threadIdx.x;
    int w = t >> 6, l = t & 63;
    int c0 = blockIdx.x * 16;

    // stage Mat -> LDS (row-major [m][k], swizzle byte ^= (row&7)<<4)
    {
        const uint4* m16 = (const uint4*)Mat; // 2048 x 16B
        for (int it = 0; it < 8; ++it){
            int idx = it * 256 + t;
            int byteoff = idx * 16;
            int row = byteoff >> 8;
            *(uint4*)(WL + (byteoff ^ ((row & 7) << 4))) = m16[idx];
        }
    }

    // gather phase: 4 columns per wave
    {
        int g = l >> 4;     // edge slot within group-of-4
        int sub = l & 15;   // 16B chunk within 256B row
        for (int jj = 0; jj < 4; ++jj){
            int j = w * 4 + jj;
            int c = c0 + j;
            int s = start[c], e = start[c + 1];
            float acc[8] = {0.f,0.f,0.f,0.f,0.f,0.f,0.f,0.f};
            int k = s;
            // 16-edge main step: 4 independent gathers in flight
            for (; k + 16 <= e; k += 16){
                uint2 pA = edges[k + g];
                uint2 pB = edges[k + 4 + g];
                uint2 pC = edges[k + 8 + g];
                uint2 pD = edges[k + 12 + g];
                uint4 xA = *(const uint4*)(Xt_in + (size_t)pA.x * 128 + sub * 8);
                uint4 xB = *(const uint4*)(Xt_in + (size_t)pB.x * 128 + sub * 8);
                uint4 xC = *(const uint4*)(Xt_in + (size_t)pC.x * 128 + sub * 8);
                uint4 xD = *(const uint4*)(Xt_in + (size_t)pD.x * 128 + sub * 8);
                float vA = __builtin_bit_cast(float, pA.y);
                float vB = __builtin_bit_cast(float, pB.y);
                float vC = __builtin_bit_cast(float, pC.y);
                float vD = __builtin_bit_cast(float, pD.y);
                acc[0] += vA * bf2f((ushort)(xA.x & 0xffffu)); acc[1] += vA * bf2f((ushort)(xA.x >> 16));
                acc[2] += vA * bf2f((ushort)(xA.y & 0xffffu)); acc[3] += vA * bf2f((ushort)(xA.y >> 16));
                acc[4] += vA * bf2f((ushort)(xA.z & 0xffffu)); acc[5] += vA * bf2f((ushort)(xA.z >> 16));
                acc[6] += vA * bf2f((ushort)(xA.w & 0xffffu)); acc[7] += vA * bf2f((ushort)(xA.w >> 16));
                acc[0] += vB * bf2f((ushort)(xB.x & 0xffffu)); acc[1] += vB * bf2f((ushort)(xB.x >> 16));
                acc[2] += vB * bf2f((ushort)(xB.y & 0xffffu)); acc[3] += vB * bf2f((ushort)(xB.y >> 16));
                acc[4] += vB * bf2f((ushort)(xB.z & 0xffffu)); acc[5] += vB * bf2f((ushort)(xB.z >> 16));
                acc[6] += vB * bf2f((ushort)(xB.w & 0xffffu)); acc[7] += vB * bf2f((ushort)(xB.w >> 16));
                acc[0] += vC * bf2f((ushort)(xC.x & 0xffffu)); acc[1] += vC * bf2f((ushort)(xC.x >> 16));
                acc[2] += vC * bf2f((ushort)(xC.y & 0xffffu)); acc[3] += vC * bf2f((ushort)(xC.y >> 16));
                acc[4] += vC * bf2f((ushort)(xC.z & 0xffffu)); acc[5] += vC * bf2f((ushort)(xC.z >> 16));
                acc[6] += vC * bf2f((ushort)(xC.w & 0xffffu)); acc[7] += vC * bf2f((ushort)(xC.w >> 16));
                acc[0] += vD * bf2f((ushort)(xD.x & 0xffffu)); acc[1] += vD * bf2f((ushort)(xD.x >> 16));
                acc[2] += vD * bf2f((ushort)(xD.y & 0xffffu)); acc[3] += vD * bf2f((ushort)(xD.y >> 16));
                acc[4] += vD * bf2f((ushort)(xD.z & 0xffffu)); acc[5] += vD * bf2f((ushort)(xD.z >> 16));
                acc[6] += vD * bf2f((ushort)(xD.w & 0xffffu)); acc[7] += vD * bf2f((ushort)(xD.w >> 16));
            }
            // 8-edge step
            if (k + 8 <= e){
                uint2 pA = edges[k + g];
                uint2 pB = edges[k + 4 + g];
                uint4 xA = *(const uint4*)(Xt_in + (size_t)pA.x * 128 + sub * 8);
                uint4 xB = *(const uint4*)(Xt_in + (size_t)pB.x * 128 + sub * 8);
                float vA = __builtin_bit_cast(float, pA.y);
                float vB = __builtin_bit_cast(float, pB.y);
                acc[0] += vA * bf2f((ushort)(xA.x & 0xffffu)); acc[1] += vA * bf2f((ushort)(xA.x >> 16));
                acc[2] += vA * bf2f((ushort)(xA.y & 0xffffu)); acc[3] += vA * bf2f((ushort)(xA.y >> 16));
                acc[4] += vA * bf2f((ushort)(xA.z & 0xffffu)); acc[5] += vA * bf2f((ushort)(xA.z >> 16));
                acc[6] += vA * bf2f((ushort)(xA.w & 0xffffu)); acc[7] += vA * bf2f((ushort)(xA.w >> 16));
                acc[0] += vB * bf2f((ushort)(xB.x & 0xffffu)); acc[1] += vB * bf2f((ushort)(xB.x >> 16));
                acc[2] += vB * bf2f((ushort)(xB.y & 0xffffu)); acc[3] += vB * bf2f((ushort)(xB.y >> 16));
                acc[4] += vB * bf2f((ushort)(xB.z & 0xffffu)); acc[5] += vB * bf2f((ushort)(xB.z >> 16));
                acc[6] += vB * bf2f((ushort)(xB.w & 0xffffu)); acc[7] += vB * bf2f((ushort)(xB.w >> 16));
                k += 8;
            }
            // guarded 4-edge tail
            for (; k < e; k += 4){
                int ke = k + g;
                uint2 p = edges[min(ke, e - 1)];
                float v = (ke < e) ? __builtin_bit_cast(float, p.y) : 0.f;
                uint4 x = *(const uint4*)(Xt_in + (size_t)p.x * 128 + sub * 8);
                acc[0] += v * bf2f((ushort)(x.x & 0xffffu)); acc[1] += v * bf2f((ushort)(x.x >> 16));
                acc[2] += v * bf2f((ushort)(x.y & 0xffffu)); acc[3] += v * bf2f((ushort)(x.y >> 16));
                acc[4] += v * bf2f((ushort)(x.z & 0xffffu)); acc[5] += v * bf2f((ushort)(x.z >> 16));
                acc[6] += v * bf2f((ushort)(x.w & 0xffffu)); acc[7] += v * bf2f((ushort)(x.w >> 16));
            }
            // reduce 4 groups
            #pragma unroll
            for (int i = 0; i < 8; ++i){
                acc[i] += __shfl_xor(acc[i], 16);
                acc[i] += __shfl_xor(acc[i], 32);
            }
            if (l < 16){
                uint4 pk;
                pk.x = (uint)f2bf(acc[0]) | ((uint)f2bf(acc[1]) << 16);
                pk.y = (uint)f2bf(acc[2]) | ((uint)f2bf(acc[3]) << 16);
                pk.z = (uint)f2bf(acc[4]) | ((uint)f2bf(acc[5]) << 16);
                pk.w = (uint)f2bf(acc[6]) | ((uint)f2bf(acc[7]) << 16);
                *(uint4*)(GL + ((j * 256 + sub * 16) ^ ((j & 7) << 4))) = pk;
            }
        }
    }
    __syncthreads();

    // GEMM phase: out[16 x 128] = G * Mat^T ; wave w owns m-range [w*32, w*32+32)
    {
        int arow = l & 15;
        int klane = (l >> 4) * 16;
        int asw = (arow & 7) << 4;
        short8 afr[4];
        for (int kc = 0; kc < 4; ++kc)
            afr[kc] = *(const short8*)(GL + ((arow * 256 + kc * 64 + klane) ^ asw));
        for (int mt = 0; mt < 2; ++mt){
            int m = w * 32 + mt * 16 + (l & 15);
            int msw = (m & 7) << 4;
            f32x4 acc4 = {0.f, 0.f, 0.f, 0.f};
            for (int kc = 0; kc < 4; ++kc){
                short8 bfr = *(const short8*)(WL + ((m * 256 + kc * 64 + klane) ^ msw));
                acc4 = __builtin_amdgcn_mfma_f32_16x16x32_bf16(afr[kc], bfr, acc4, 0, 0, 0);
            }
            int crow_base = c0 + ((l >> 4) << 2);
            #pragma unroll
            for (int q = 0; q < 4; ++q){
                int c = crow_base + q;
                float val = acc4[q];
                if (MODE == 1){
                    val += bf2f(Bt[c * MDIM + m]);
                    val = fmaxf(val, 0.f);
                }
                outp[c * MDIM + m] = f2bf(val);
            }
        }
    }
}

extern "C" void kernel_launch(void* const* d_in, const int* in_sizes, int n_in,
                              void* d_out, int out_size, void* d_ws, size_t ws_size,
                              hipStream_t stream){
    const float* X0 = (const float*)d_in[0];
    const float* U  = (const float*)d_in[1];
    const float* W  = (const float*)d_in[2];
    const float* Om = (const float*)d_in[3];
    const float* Av = (const float*)d_in[4];
    const int*   Ar = (const int*)d_in[5];
    const int*   Ac = (const int*)d_in[6];
    (void)in_sizes; (void)n_in; (void)out_size; (void)ws_size;

    char* ws = (char*)d_ws;
    size_t off = 0;
    auto alloc = [&](size_t bytes) -> char* {
        char* p = ws + off;
        off += (bytes + 255) & ~(size_t)255;
        return p;
    };
    int*    start = (int*)alloc((NCOL + 1) * 4);        //  80 KB
    uint2*  edges = (uint2*)alloc(NEDGE * 8);           //  2.56 MB
    ushort* Wp    = (ushort*)alloc(MDIM * MDIM * 2);    //  32 KB
    ushort* Omb   = (ushort*)alloc(MDIM * MDIM * 2);    //  32 KB
    ushort* P0    = (ushort*)alloc(NCOL * MDIM * 2);    //  5.12 MB

    // cnt/cursor live in P0's space (dead before k_tin writes it)
    int* cnt    = (int*)P0;
    int* cursor = cnt + NCOL;

    // d_out (10.24 MB f32) hosts P1 + Bt until the final transpose
    ushort* P1   = (ushort*)d_out;
    ushort* BtBF = (ushort*)((char*)d_out + NCOL * MDIM * 2);

    k_zero<<<(2 * NCOL + 255) / 256, 256, 0, stream>>>(cnt);
    k_hist<<<(NEDGE + 255) / 256, 256, 0, stream>>>(Ac, cnt);
    k_scan<<<1, 256, 0, stream>>>(cnt, start);
    k_scatter<<<(NEDGE + 255) / 256, 256, 0, stream>>>(Ar, Ac, Av, start, cursor, edges);
    k_project<<<32, 256, 0, stream>>>(W, Wp);
    k_cvt<<<64, 256, 0, stream>>>(Om, Omb);
    k_tin<<<dim3(313, 2), 256, 0, stream>>>(X0, U, P0, P1);
    // Bt = ((Omega_1 @ U) @ A)^T, stored bf16
    k_fused<0><<<1250, 256, 0, stream>>>(P1, Omb, nullptr, BtBF, start, edges);
    const ushort* cur = P0; ushort* nxt = P1;
    for (int i = 0; i < NITER; ++i){
        k_fused<1><<<1250, 256, 0, stream>>>(cur, Wp, BtBF, nxt, start, edges);
        ushort* tmp = (ushort*)cur; cur = nxt; nxt = tmp;
    }
    // NITER even -> cur == P0 (ws); k_tout overwrites all of d_out (P1/Bt dead)
    k_tout<<<313, 256, 0, stream>>>(cur, (float*)d_out);
}

// Round 6
// 622.179 us; speedup vs baseline: 2.1156x; 1.3398x over previous
//
#include <hip/hip_runtime.h>

#define MDIM 128
#define NCOL 20000
#define NEDGE 320000
#define NITER 30
#define FKAPPA 0.99f

typedef unsigned int uint;
typedef unsigned short ushort;
typedef __attribute__((ext_vector_type(8))) short short8;
typedef __attribute__((ext_vector_type(4))) float f32x4;

__device__ __forceinline__ float bf2f(ushort b){
    uint u = ((uint)b) << 16;
    return __builtin_bit_cast(float, u);
}
__device__ __forceinline__ ushort f2bf(float f){
    uint u = __builtin_bit_cast(uint, f);
    uint r = (u + 0x7fffu + ((u >> 16) & 1u)) >> 16;
    return (ushort)r;
}

// ---------------- CSC build ----------------
__global__ void k_zero(int* __restrict__ p){
    int i = blockIdx.x * 256 + threadIdx.x;
    if (i < 2 * NCOL) p[i] = 0;
}

__global__ void k_hist(const int* __restrict__ cols, int* __restrict__ cnt){
    int e = blockIdx.x * 256 + threadIdx.x;
    if (e < NEDGE) atomicAdd(&cnt[cols[e]], 1);
}

__global__ void k_scan(const int* __restrict__ cnt, int* __restrict__ start){
    __shared__ int lds[256];
    const int SEG = (NCOL + 255) / 256; // 79
    int t = threadIdx.x;
    int lo = t * SEG;
    int hi = min(lo + SEG, NCOL);
    int s = 0;
    for (int i = lo; i < hi; ++i) s += cnt[i];
    lds[t] = s;
    __syncthreads();
    for (int off = 1; off < 256; off <<= 1){
        int v = (t >= off) ? lds[t - off] : 0;
        __syncthreads();
        lds[t] += v;
        __syncthreads();
    }
    int run = (t > 0) ? lds[t - 1] : 0;
    for (int i = lo; i < hi; ++i){ start[i] = run; run += cnt[i]; }
    if (hi == NCOL && lo < NCOL) start[NCOL] = run;
}

// edges[p] = { row, f32_bits(val) }
__global__ void k_scatter(const int* __restrict__ rows, const int* __restrict__ cols,
                          const float* __restrict__ vals, const int* __restrict__ start,
                          int* __restrict__ cursor, uint2* __restrict__ edges){
    int e = blockIdx.x * 256 + threadIdx.x;
    if (e < NEDGE){
        int c = cols[e];
        int p = start[c] + atomicAdd(&cursor[c], 1);
        edges[p] = make_uint2((uint)rows[e], __builtin_bit_cast(uint, vals[e]));
    }
}

// ---------------- L-inf projection of W ----------------
__global__ void k_project(const float* __restrict__ W, ushort* __restrict__ Wp){
    int row = blockIdx.x * 4 + (threadIdx.x >> 6);
    int l = threadIdx.x & 63;
    const float* wr = W + row * MDIM;
    float w0 = wr[l], w1 = wr[l + 64];
    float a0 = fabsf(w0), a1 = fabsf(w1);
    float s = a0 + a1, mx = fmaxf(a0, a1);
    for (int off = 32; off; off >>= 1){
        s += __shfl_xor(s, off);
        mx = fmaxf(mx, __shfl_xor(mx, off));
    }
    if (s > FKAPPA){
        float tlo = 0.f, thi = mx;
        for (int it = 0; it < 48; ++it){
            float th = 0.5f * (tlo + thi);
            float f = fmaxf(a0 - th, 0.f) + fmaxf(a1 - th, 0.f);
            for (int off = 32; off; off >>= 1) f += __shfl_xor(f, off);
            if (f > FKAPPA) tlo = th; else thi = th;
        }
        float th = 0.5f * (tlo + thi);
        w0 = copysignf(fmaxf(a0 - th, 0.f), w0);
        w1 = copysignf(fmaxf(a1 - th, 0.f), w1);
    }
    Wp[row * MDIM + l] = f2bf(w0);
    Wp[row * MDIM + l + 64] = f2bf(w1);
}

__global__ void k_cvt(const float* __restrict__ src, ushort* __restrict__ dst){
    int i = blockIdx.x * 256 + threadIdx.x;
    if (i < MDIM * MDIM) dst[i] = f2bf(src[i]);
}

// ---------------- transposes f32 [128][N] <-> bf16 [N][128] ----------------
__global__ void k_tin(const float* __restrict__ X0, const float* __restrict__ U,
                      ushort* __restrict__ Xt, ushort* __restrict__ Ut){
    __shared__ ushort tile[128 * 66];
    const float* src = blockIdx.y ? U : X0;
    ushort* dst = blockIdx.y ? Ut : Xt;
    int c0 = blockIdx.x * 64;
    int t = threadIdx.x;
    for (int it = 0; it < 32; ++it){
        int le = it * 256 + t;
        int j = le & 63, m = le >> 6;
        int c = c0 + j;
        tile[m * 66 + j] = (c < NCOL) ? f2bf(src[m * NCOL + c]) : (ushort)0;
    }
    __syncthreads();
    for (int it = 0; it < 32; ++it){
        int le = it * 256 + t;
        int m = le & 127, jc = le >> 7;
        int c = c0 + jc;
        if (c < NCOL) dst[c * MDIM + m] = tile[m * 66 + jc];
    }
}

__global__ void k_tout(const ushort* __restrict__ Xt, float* __restrict__ out){
    __shared__ ushort tile[128 * 66];
    int c0 = blockIdx.x * 64;
    int t = threadIdx.x;
    for (int it = 0; it < 32; ++it){
        int le = it * 256 + t;
        int m = le & 127, jc = le >> 7;
        int c = c0 + jc;
        tile[m * 66 + jc] = (c < NCOL) ? Xt[c * MDIM + m] : (ushort)0;
    }
    __syncthreads();
    for (int it = 0; it < 32; ++it){
        int le = it * 256 + t;
        int j = le & 63, m = le >> 6;
        int c = c0 + j;
        if (c < NCOL) out[m * NCOL + c] = bf2f(tile[m * 66 + j]);
    }
}

__device__ __forceinline__ void fma8(float* acc, uint4 x, float v){
    acc[0] += v * bf2f((ushort)(x.x & 0xffffu)); acc[1] += v * bf2f((ushort)(x.x >> 16));
    acc[2] += v * bf2f((ushort)(x.y & 0xffffu)); acc[3] += v * bf2f((ushort)(x.y >> 16));
    acc[4] += v * bf2f((ushort)(x.z & 0xffffu)); acc[5] += v * bf2f((ushort)(x.z >> 16));
    acc[6] += v * bf2f((ushort)(x.w & 0xffffu)); acc[7] += v * bf2f((ushort)(x.w >> 16));
}

// ---------------- fused iteration ----------------
// out[c][m] = phi( sum_k (X@A)^T[c][k] * Mat[m][k] + Bt[c][m] )
// 16 columns per block (1250 blocks), 4 waves. Gather: wave-wide edge preload
// (one load covers <=64 edges), row/val via bpermute, 4 x-gathers in flight.
// Mat panel (per-wave 32x128) lives in registers -> LDS is only 4 KB.
template<int MODE>
__global__ __launch_bounds__(256, 5) void k_fused(const ushort* __restrict__ Xt_in,
                        const ushort* __restrict__ Mat,
                        const ushort* __restrict__ Bt,
                        ushort* __restrict__ outp,
                        const int* __restrict__ start,
                        const uint2* __restrict__ edges){
    __shared__ alignas(16) char GL[4 * 1024];  // G[16][128] bf16, XOR-swizzled rows
    int t = threadIdx.x;
    int w = t >> 6, l = t & 63;
    int c0 = blockIdx.x * 16;
    int g = l >> 4;     // edge slot within group-of-4
    int sub = l & 15;   // 16B chunk within 256B row

    // start[] values for this wave's 4 columns (uniform -> SGPRs)
    int sa[5];
    #pragma unroll
    for (int i = 0; i < 5; ++i) sa[i] = start[c0 + w * 4 + i];

    // gather phase: 4 columns per wave, edge vectors software-pipelined
    {
        auto preload = [&](int jj) -> uint2 {
            int s = sa[jj], e = sa[jj + 1];
            int idx = (e > s) ? min(s + l, e - 1) : 0;
            return edges[idx];
        };
        uint2 my = preload(0);
        #pragma unroll
        for (int jj = 0; jj < 4; ++jj){
            uint2 nxt = (jj < 3) ? preload(jj + 1) : my;
            int s = sa[jj], e = sa[jj + 1];
            int d = e - s;
            int dd = min(d, 64);
            float acc[8] = {0.f,0.f,0.f,0.f,0.f,0.f,0.f,0.f};
            int k = 0;
            // 16-edge steps: 4 independent x-gathers in flight, edge data via bpermute
            for (; k + 16 <= dd; k += 16){
                int r0 = __shfl((int)my.x, k + g);
                int r1 = __shfl((int)my.x, k + 4 + g);
                int r2 = __shfl((int)my.x, k + 8 + g);
                int r3 = __shfl((int)my.x, k + 12 + g);
                float v0 = __builtin_bit_cast(float, __shfl((int)my.y, k + g));
                float v1 = __builtin_bit_cast(float, __shfl((int)my.y, k + 4 + g));
                float v2 = __builtin_bit_cast(float, __shfl((int)my.y, k + 8 + g));
                float v3 = __builtin_bit_cast(float, __shfl((int)my.y, k + 12 + g));
                uint4 x0 = *(const uint4*)(Xt_in + (size_t)(uint)r0 * 128 + sub * 8);
                uint4 x1 = *(const uint4*)(Xt_in + (size_t)(uint)r1 * 128 + sub * 8);
                uint4 x2 = *(const uint4*)(Xt_in + (size_t)(uint)r2 * 128 + sub * 8);
                uint4 x3 = *(const uint4*)(Xt_in + (size_t)(uint)r3 * 128 + sub * 8);
                fma8(acc, x0, v0); fma8(acc, x1, v1); fma8(acc, x2, v2); fma8(acc, x3, v3);
            }
            // guarded 4-edge bpermute steps (<=3 iters)
            for (; k < dd; k += 4){
                int ke = k + g;
                int sel = min(ke, dd - 1);
                int rr = __shfl((int)my.x, sel);
                float vv = __builtin_bit_cast(float, __shfl((int)my.y, sel));
                vv = (ke < dd) ? vv : 0.f;
                uint4 x = *(const uint4*)(Xt_in + (size_t)(uint)rr * 128 + sub * 8);
                fma8(acc, x, vv);
            }
            // rare slow path: degree > 64
            if (d > 64){
                for (int k2 = sa[jj] + 64; k2 < e; k2 += 4){
                    int ke = k2 + g;
                    uint2 p = edges[min(ke, e - 1)];
                    float vv = (ke < e) ? __builtin_bit_cast(float, p.y) : 0.f;
                    uint4 x = *(const uint4*)(Xt_in + (size_t)p.x * 128 + sub * 8);
                    fma8(acc, x, vv);
                }
            }
            // reduce 4 groups
            #pragma unroll
            for (int i = 0; i < 8; ++i){
                acc[i] += __shfl_xor(acc[i], 16);
                acc[i] += __shfl_xor(acc[i], 32);
            }
            int j = w * 4 + jj;
            if (l < 16){
                uint4 pk;
                pk.x = (uint)f2bf(acc[0]) | ((uint)f2bf(acc[1]) << 16);
                pk.y = (uint)f2bf(acc[2]) | ((uint)f2bf(acc[3]) << 16);
                pk.z = (uint)f2bf(acc[4]) | ((uint)f2bf(acc[5]) << 16);
                pk.w = (uint)f2bf(acc[6]) | ((uint)f2bf(acc[7]) << 16);
                *(uint4*)(GL + ((j * 256 + sub * 16) ^ ((j & 7) << 4))) = pk;
            }
            my = nxt;
        }
    }

    // keep Mat fragment loads out of the gather loop (register pressure)
    __builtin_amdgcn_sched_barrier(0);

    // Mat B-panel for this wave: rows [w*32, w*32+32), all k -> 8 short8 fragments
    short8 bfr[2][4];
    #pragma unroll
    for (int mt = 0; mt < 2; ++mt){
        int m = w * 32 + mt * 16 + (l & 15);
        #pragma unroll
        for (int kc = 0; kc < 4; ++kc)
            bfr[mt][kc] = *(const short8*)(Mat + m * MDIM + kc * 32 + (l >> 4) * 8);
    }
    __syncthreads();

    // GEMM phase: out[16 x 128] = G * Mat^T ; wave w owns m-range [w*32, w*32+32)
    {
        int arow = l & 15;
        int klane = (l >> 4) * 16;
        int asw = (arow & 7) << 4;
        short8 afr[4];
        #pragma unroll
        for (int kc = 0; kc < 4; ++kc)
            afr[kc] = *(const short8*)(GL + ((arow * 256 + kc * 64 + klane) ^ asw));
        #pragma unroll
        for (int mt = 0; mt < 2; ++mt){
            int m = w * 32 + mt * 16 + (l & 15);
            f32x4 acc4 = {0.f, 0.f, 0.f, 0.f};
            #pragma unroll
            for (int kc = 0; kc < 4; ++kc)
                acc4 = __builtin_amdgcn_mfma_f32_16x16x32_bf16(afr[kc], bfr[mt][kc], acc4, 0, 0, 0);
            int crow_base = c0 + ((l >> 4) << 2);
            #pragma unroll
            for (int q = 0; q < 4; ++q){
                int c = crow_base + q;
                float val = acc4[q];
                if (MODE == 1){
                    val += bf2f(Bt[c * MDIM + m]);
                    val = fmaxf(val, 0.f);
                }
                outp[c * MDIM + m] = f2bf(val);
            }
        }
    }
}

extern "C" void kernel_launch(void* const* d_in, const int* in_sizes, int n_in,
                              void* d_out, int out_size, void* d_ws, size_t ws_size,
                              hipStream_t stream){
    const float* X0 = (const float*)d_in[0];
    const float* U  = (const float*)d_in[1];
    const float* W  = (const float*)d_in[2];
    const float* Om = (const float*)d_in[3];
    const float* Av = (const float*)d_in[4];
    const int*   Ar = (const int*)d_in[5];
    const int*   Ac = (const int*)d_in[6];
    (void)in_sizes; (void)n_in; (void)out_size; (void)ws_size;

    char* ws = (char*)d_ws;
    size_t off = 0;
    auto alloc = [&](size_t bytes) -> char* {
        char* p = ws + off;
        off += (bytes + 255) & ~(size_t)255;
        return p;
    };
    int*    start = (int*)alloc((NCOL + 1) * 4);        //  80 KB
    uint2*  edges = (uint2*)alloc(NEDGE * 8);           //  2.56 MB
    ushort* Wp    = (ushort*)alloc(MDIM * MDIM * 2);    //  32 KB
    ushort* Omb   = (ushort*)alloc(MDIM * MDIM * 2);    //  32 KB
    ushort* P0    = (ushort*)alloc(NCOL * MDIM * 2);    //  5.12 MB

    // cnt/cursor live in P0's space (dead before k_tin writes it)
    int* cnt    = (int*)P0;
    int* cursor = cnt + NCOL;

    // d_out (10.24 MB f32) hosts P1 + Bt until the final transpose
    ushort* P1   = (ushort*)d_out;
    ushort* BtBF = (ushort*)((char*)d_out + NCOL * MDIM * 2);

    k_zero<<<(2 * NCOL + 255) / 256, 256, 0, stream>>>(cnt);
    k_hist<<<(NEDGE + 255) / 256, 256, 0, stream>>>(Ac, cnt);
    k_scan<<<1, 256, 0, stream>>>(cnt, start);
    k_scatter<<<(NEDGE + 255) / 256, 256, 0, stream>>>(Ar, Ac, Av, start, cursor, edges);
    k_project<<<32, 256, 0, stream>>>(W, Wp);
    k_cvt<<<64, 256, 0, stream>>>(Om, Omb);
    k_tin<<<dim3(313, 2), 256, 0, stream>>>(X0, U, P0, P1);
    // Bt = ((Omega_1 @ U) @ A)^T, stored bf16
    k_fused<0><<<1250, 256, 0, stream>>>(P1, Omb, nullptr, BtBF, start, edges);
    const ushort* cur = P0; ushort* nxt = P1;
    for (int i = 0; i < NITER; ++i){
        k_fused<1><<<1250, 256, 0, stream>>>(cur, Wp, BtBF, nxt, start, edges);
        ushort* tmp = (ushort*)cur; cur = nxt; nxt = tmp;
    }
    // NITER even -> cur == P0 (ws); k_tout overwrites all of d_out (P1/Bt dead)
    k_tout<<<313, 256, 0, stream>>>(cur, (float*)d_out);
}

// Round 7
// 592.701 us; speedup vs baseline: 2.2208x; 1.0497x over previous
//
#include <hip/hip_runtime.h>

#define MDIM 128
#define NCOL 20000
#define NEDGE 320000
#define NITER 30
#define FKAPPA 0.99f

typedef unsigned int uint;
typedef unsigned short ushort;
typedef __attribute__((ext_vector_type(8))) short short8;
typedef __attribute__((ext_vector_type(4))) float f32x4;

__device__ __forceinline__ float bf2f(ushort b){
    uint u = ((uint)b) << 16;
    return __builtin_bit_cast(float, u);
}
__device__ __forceinline__ ushort f2bf(float f){
    uint u = __builtin_bit_cast(uint, f);
    uint r = (u + 0x7fffu + ((u >> 16) & 1u)) >> 16;
    return (ushort)r;
}

// ---------------- CSC build ----------------
__global__ void k_zero(int* __restrict__ p){
    int i = blockIdx.x * 256 + threadIdx.x;
    if (i < 2 * NCOL) p[i] = 0;
}

__global__ void k_hist(const int* __restrict__ cols, int* __restrict__ cnt){
    int e = blockIdx.x * 256 + threadIdx.x;
    if (e < NEDGE) atomicAdd(&cnt[cols[e]], 1);
}

__global__ void k_scan(const int* __restrict__ cnt, int* __restrict__ start){
    __shared__ int lds[256];
    const int SEG = (NCOL + 255) / 256; // 79
    int t = threadIdx.x;
    int lo = t * SEG;
    int hi = min(lo + SEG, NCOL);
    int s = 0;
    for (int i = lo; i < hi; ++i) s += cnt[i];
    lds[t] = s;
    __syncthreads();
    for (int off = 1; off < 256; off <<= 1){
        int v = (t >= off) ? lds[t - off] : 0;
        __syncthreads();
        lds[t] += v;
        __syncthreads();
    }
    int run = (t > 0) ? lds[t - 1] : 0;
    for (int i = lo; i < hi; ++i){ start[i] = run; run += cnt[i]; }
    if (hi == NCOL && lo < NCOL) start[NCOL] = run;
}

// edges[p] = { row, f32_bits(val) }
__global__ void k_scatter(const int* __restrict__ rows, const int* __restrict__ cols,
                          const float* __restrict__ vals, const int* __restrict__ start,
                          int* __restrict__ cursor, uint2* __restrict__ edges){
    int e = blockIdx.x * 256 + threadIdx.x;
    if (e < NEDGE){
        int c = cols[e];
        int p = start[c] + atomicAdd(&cursor[c], 1);
        edges[p] = make_uint2((uint)rows[e], __builtin_bit_cast(uint, vals[e]));
    }
}

// ---------------- L-inf projection of W ----------------
__global__ void k_project(const float* __restrict__ W, ushort* __restrict__ Wp){
    int row = blockIdx.x * 4 + (threadIdx.x >> 6);
    int l = threadIdx.x & 63;
    const float* wr = W + row * MDIM;
    float w0 = wr[l], w1 = wr[l + 64];
    float a0 = fabsf(w0), a1 = fabsf(w1);
    float s = a0 + a1, mx = fmaxf(a0, a1);
    for (int off = 32; off; off >>= 1){
        s += __shfl_xor(s, off);
        mx = fmaxf(mx, __shfl_xor(mx, off));
    }
    if (s > FKAPPA){
        float tlo = 0.f, thi = mx;
        for (int it = 0; it < 48; ++it){
            float th = 0.5f * (tlo + thi);
            float f = fmaxf(a0 - th, 0.f) + fmaxf(a1 - th, 0.f);
            for (int off = 32; off; off >>= 1) f += __shfl_xor(f, off);
            if (f > FKAPPA) tlo = th; else thi = th;
        }
        float th = 0.5f * (tlo + thi);
        w0 = copysignf(fmaxf(a0 - th, 0.f), w0);
        w1 = copysignf(fmaxf(a1 - th, 0.f), w1);
    }
    Wp[row * MDIM + l] = f2bf(w0);
    Wp[row * MDIM + l + 64] = f2bf(w1);
}

__global__ void k_cvt(const float* __restrict__ src, ushort* __restrict__ dst){
    int i = blockIdx.x * 256 + threadIdx.x;
    if (i < MDIM * MDIM) dst[i] = f2bf(src[i]);
}

// ---------------- transposes f32 [128][N] <-> bf16 [N][128] ----------------
__global__ void k_tin(const float* __restrict__ X0, const float* __restrict__ U,
                      ushort* __restrict__ Xt, ushort* __restrict__ Ut){
    __shared__ ushort tile[128 * 66];
    const float* src = blockIdx.y ? U : X0;
    ushort* dst = blockIdx.y ? Ut : Xt;
    int c0 = blockIdx.x * 64;
    int t = threadIdx.x;
    for (int it = 0; it < 32; ++it){
        int le = it * 256 + t;
        int j = le & 63, m = le >> 6;
        int c = c0 + j;
        tile[m * 66 + j] = (c < NCOL) ? f2bf(src[m * NCOL + c]) : (ushort)0;
    }
    __syncthreads();
    for (int it = 0; it < 32; ++it){
        int le = it * 256 + t;
        int m = le & 127, jc = le >> 7;
        int c = c0 + jc;
        if (c < NCOL) dst[c * MDIM + m] = tile[m * 66 + jc];
    }
}

__global__ void k_tout(const ushort* __restrict__ Xt, float* __restrict__ out){
    __shared__ ushort tile[128 * 66];
    int c0 = blockIdx.x * 64;
    int t = threadIdx.x;
    for (int it = 0; it < 32; ++it){
        int le = it * 256 + t;
        int m = le & 127, jc = le >> 7;
        int c = c0 + jc;
        tile[m * 66 + jc] = (c < NCOL) ? Xt[c * MDIM + m] : (ushort)0;
    }
    __syncthreads();
    for (int it = 0; it < 32; ++it){
        int le = it * 256 + t;
        int j = le & 63, m = le >> 6;
        int c = c0 + j;
        if (c < NCOL) out[m * NCOL + c] = bf2f(tile[m * 66 + j]);
    }
}

__device__ __forceinline__ void fma8(float* acc, uint4 x, float v){
    acc[0] += v * bf2f((ushort)(x.x & 0xffffu)); acc[1] += v * bf2f((ushort)(x.x >> 16));
    acc[2] += v * bf2f((ushort)(x.y & 0xffffu)); acc[3] += v * bf2f((ushort)(x.y >> 16));
    acc[4] += v * bf2f((ushort)(x.z & 0xffffu)); acc[5] += v * bf2f((ushort)(x.z >> 16));
    acc[6] += v * bf2f((ushort)(x.w & 0xffffu)); acc[7] += v * bf2f((ushort)(x.w >> 16));
}

// ---------------- fused iteration ----------------
// out[c][m] = phi( sum_k (X@A)^T[c][k] * Mat[m][k] + Bt[c][m] )
// 16 columns per block (1250 blocks), 4 waves. Per column: ONE straight-line
// guarded block (4 loads if deg<=16, 8 loads if deg<=32, all issued before
// any FMA; clamped slots re-read the last row -> L1 hit, v=0 -> no traffic).
// Edge descriptors for all 4 columns preloaded wave-wide at entry.
template<int MODE>
__global__ __launch_bounds__(256, 5) void k_fused(const ushort* __restrict__ Xt_in,
                        const ushort* __restrict__ Mat,
                        const ushort* __restrict__ Bt,
                        ushort* __restrict__ outp,
                        const int* __restrict__ start,
                        const uint2* __restrict__ edges){
    __shared__ alignas(16) char GL[4 * 1024];  // G[16][128] bf16, XOR-swizzled rows
    int t = threadIdx.x;
    int w = t >> 6, l = t & 63;
    int c0 = blockIdx.x * 16;
    int g = l >> 4;     // edge slot within group-of-4
    int sub = l & 15;   // 16B chunk within 256B row

    // start[] values for this wave's 4 columns (uniform -> SGPRs)
    int sa[5];
    #pragma unroll
    for (int i = 0; i < 5; ++i) sa[i] = start[c0 + w * 4 + i];

    // preload edge descriptor vectors for all 4 columns (4 loads in flight)
    uint2 myv[4];
    #pragma unroll
    for (int jj = 0; jj < 4; ++jj){
        int s = sa[jj], e = sa[jj + 1];
        int idx = (e > s) ? min(s + l, e - 1) : 0;
        myv[jj] = edges[idx];
    }

    #pragma unroll
    for (int jj = 0; jj < 4; ++jj){
        int s = sa[jj], e = sa[jj + 1];
        int d = e - s;
        float acc[8] = {0.f,0.f,0.f,0.f,0.f,0.f,0.f,0.f};
        if (d > 0){
            uint2 my = myv[jj];
            if (d <= 16){
                // 16-slot straight-line block: 4 loads in flight
                int r[4]; float v[4];
                #pragma unroll
                for (int b = 0; b < 4; ++b){
                    int slot = b * 4 + g;
                    int sel = min(slot, d - 1);
                    r[b] = __shfl((int)my.x, sel);
                    float vt = __builtin_bit_cast(float, __shfl((int)my.y, sel));
                    v[b] = (slot < d) ? vt : 0.f;
                }
                uint4 x[4];
                #pragma unroll
                for (int b = 0; b < 4; ++b)
                    x[b] = *(const uint4*)(Xt_in + (size_t)(uint)r[b] * 128 + sub * 8);
                #pragma unroll
                for (int b = 0; b < 4; ++b) fma8(acc, x[b], v[b]);
            } else {
                // 32-slot straight-line block: 8 loads in flight
                int r[8]; float v[8];
                #pragma unroll
                for (int b = 0; b < 8; ++b){
                    int slot = b * 4 + g;
                    int sel = min(slot, min(d, 64) - 1);
                    r[b] = __shfl((int)my.x, sel);
                    float vt = __builtin_bit_cast(float, __shfl((int)my.y, sel));
                    v[b] = (slot < d) ? vt : 0.f;
                }
                uint4 x[8];
                #pragma unroll
                for (int b = 0; b < 8; ++b)
                    x[b] = *(const uint4*)(Xt_in + (size_t)(uint)r[b] * 128 + sub * 8);
                #pragma unroll
                for (int b = 0; b < 8; ++b) fma8(acc, x[b], v[b]);
                // rare remainder: degree > 32 (~2 columns in 20000)
                if (d > 32){
                    for (int k2 = s + 32; k2 < e; k2 += 4){
                        int ke = k2 + g;
                        uint2 p = edges[min(ke, e - 1)];
                        float vv = (ke < e) ? __builtin_bit_cast(float, p.y) : 0.f;
                        uint4 xx = *(const uint4*)(Xt_in + (size_t)p.x * 128 + sub * 8);
                        fma8(acc, xx, vv);
                    }
                }
            }
        }
        // reduce 4 groups
        #pragma unroll
        for (int i = 0; i < 8; ++i){
            acc[i] += __shfl_xor(acc[i], 16);
            acc[i] += __shfl_xor(acc[i], 32);
        }
        int j = w * 4 + jj;
        if (l < 16){
            uint4 pk;
            pk.x = (uint)f2bf(acc[0]) | ((uint)f2bf(acc[1]) << 16);
            pk.y = (uint)f2bf(acc[2]) | ((uint)f2bf(acc[3]) << 16);
            pk.z = (uint)f2bf(acc[4]) | ((uint)f2bf(acc[5]) << 16);
            pk.w = (uint)f2bf(acc[6]) | ((uint)f2bf(acc[7]) << 16);
            *(uint4*)(GL + ((j * 256 + sub * 16) ^ ((j & 7) << 4))) = pk;
        }
    }

    // keep Mat fragment loads out of the gather loop (register pressure)
    __builtin_amdgcn_sched_barrier(0);

    // Mat B-panel for this wave: rows [w*32, w*32+32), all k -> 8 short8 fragments
    short8 bfr[2][4];
    #pragma unroll
    for (int mt = 0; mt < 2; ++mt){
        int m = w * 32 + mt * 16 + (l & 15);
        #pragma unroll
        for (int kc = 0; kc < 4; ++kc)
            bfr[mt][kc] = *(const short8*)(Mat + m * MDIM + kc * 32 + (l >> 4) * 8);
    }
    __syncthreads();

    // GEMM phase: out[16 x 128] = G * Mat^T ; wave w owns m-range [w*32, w*32+32)
    {
        int arow = l & 15;
        int klane = (l >> 4) * 16;
        int asw = (arow & 7) << 4;
        short8 afr[4];
        #pragma unroll
        for (int kc = 0; kc < 4; ++kc)
            afr[kc] = *(const short8*)(GL + ((arow * 256 + kc * 64 + klane) ^ asw));
        #pragma unroll
        for (int mt = 0; mt < 2; ++mt){
            int m = w * 32 + mt * 16 + (l & 15);
            f32x4 acc4 = {0.f, 0.f, 0.f, 0.f};
            #pragma unroll
            for (int kc = 0; kc < 4; ++kc)
                acc4 = __builtin_amdgcn_mfma_f32_16x16x32_bf16(afr[kc], bfr[mt][kc], acc4, 0, 0, 0);
            int crow_base = c0 + ((l >> 4) << 2);
            #pragma unroll
            for (int q = 0; q < 4; ++q){
                int c = crow_base + q;
                float val = acc4[q];
                if (MODE == 1){
                    val += bf2f(Bt[c * MDIM + m]);
                    val = fmaxf(val, 0.f);
                }
                outp[c * MDIM + m] = f2bf(val);
            }
        }
    }
}

extern "C" void kernel_launch(void* const* d_in, const int* in_sizes, int n_in,
                              void* d_out, int out_size, void* d_ws, size_t ws_size,
                              hipStream_t stream){
    const float* X0 = (const float*)d_in[0];
    const float* U  = (const float*)d_in[1];
    const float* W  = (const float*)d_in[2];
    const float* Om = (const float*)d_in[3];
    const float* Av = (const float*)d_in[4];
    const int*   Ar = (const int*)d_in[5];
    const int*   Ac = (const int*)d_in[6];
    (void)in_sizes; (void)n_in; (void)out_size; (void)ws_size;

    char* ws = (char*)d_ws;
    size_t off = 0;
    auto alloc = [&](size_t bytes) -> char* {
        char* p = ws + off;
        off += (bytes + 255) & ~(size_t)255;
        return p;
    };
    int*    start = (int*)alloc((NCOL + 1) * 4);        //  80 KB
    uint2*  edges = (uint2*)alloc(NEDGE * 8);           //  2.56 MB
    ushort* Wp    = (ushort*)alloc(MDIM * MDIM * 2);    //  32 KB
    ushort* Omb   = (ushort*)alloc(MDIM * MDIM * 2);    //  32 KB
    ushort* P0    = (ushort*)alloc(NCOL * MDIM * 2);    //  5.12 MB

    // cnt/cursor live in P0's space (dead before k_tin writes it)
    int* cnt    = (int*)P0;
    int* cursor = cnt + NCOL;

    // d_out (10.24 MB f32) hosts P1 + Bt until the final transpose
    ushort* P1   = (ushort*)d_out;
    ushort* BtBF = (ushort*)((char*)d_out + NCOL * MDIM * 2);

    k_zero<<<(2 * NCOL + 255) / 256, 256, 0, stream>>>(cnt);
    k_hist<<<(NEDGE + 255) / 256, 256, 0, stream>>>(Ac, cnt);
    k_scan<<<1, 256, 0, stream>>>(cnt, start);
    k_scatter<<<(NEDGE + 255) / 256, 256, 0, stream>>>(Ar, Ac, Av, start, cursor, edges);
    k_project<<<32, 256, 0, stream>>>(W, Wp);
    k_cvt<<<64, 256, 0, stream>>>(Om, Omb);
    k_tin<<<dim3(313, 2), 256, 0, stream>>>(X0, U, P0, P1);
    // Bt = ((Omega_1 @ U) @ A)^T, stored bf16
    k_fused<0><<<1250, 256, 0, stream>>>(P1, Omb, nullptr, BtBF, start, edges);
    const ushort* cur = P0; ushort* nxt = P1;
    for (int i = 0; i < NITER; ++i){
        k_fused<1><<<1250, 256, 0, stream>>>(cur, Wp, BtBF, nxt, start, edges);
        ushort* tmp = (ushort*)cur; cur = nxt; nxt = tmp;
    }
    // NITER even -> cur == P0 (ws); k_tout overwrites all of d_out (P1/Bt dead)
    k_tout<<<313, 256, 0, stream>>>(cur, (float*)d_out);
}